// Round 2
// baseline (183.661 us; speedup 1.0000x reference)
//
#include <hip/hip_runtime.h>
#include <stdint.h>

typedef unsigned long long u64;

// Problem constants
#define NN 32
#define CC 256
#define HH 28
#define WW 28
#define PP 784          // H*W
#define NHW 25088       // N*H*W  (per-channel BN count)
#define WPO 36          // packed words per output channel: 9 taps * 4 words

// ---------------------------------------------------------------------------
// K0: zero the stats accumulators
// ---------------------------------------------------------------------------
__global__ __launch_bounds__(256) void zero_stats(int* s1i, u64* s1q, double* s2s, double* s2q) {
    int c = threadIdx.x;
    s1i[c] = 0; s1q[c] = 0ull; s2s[c] = 0.0; s2q[c] = 0.0;
}

// ---------------------------------------------------------------------------
// K1: binarize + bit-pack x (NCHW f32) -> xp [N][P][4] u64 (bit c%64 of word c/64)
// ---------------------------------------------------------------------------
__global__ __launch_bounds__(256) void pack_x(const float* __restrict__ x, u64* __restrict__ xp) {
    int h = blockIdx.x, n = blockIdx.y;
    int tid = threadIdx.x, lane = tid & 63, g = tid >> 6;
    int c = tid;
    const float* px = x + (((size_t)n * CC + c) * PP) + h * WW;
    float vals[28];
#pragma unroll
    for (int k = 0; k < 7; ++k) ((float4*)vals)[k] = ((const float4*)px)[k];
    u64* dst = xp + ((size_t)n * PP + h * WW) * 4 + g;
#pragma unroll
    for (int i = 0; i < 28; ++i) {
        u64 m = __ballot(vals[i] > 0.0f);
        if (lane == 0) dst[(size_t)i * 4] = m;
    }
}

// ---------------------------------------------------------------------------
// K1b: binarize + pack weights [O][C][3][3] -> wp [O][9][4] u64
// ---------------------------------------------------------------------------
__global__ __launch_bounds__(256) void pack_w(const float* __restrict__ w, u64* __restrict__ wp) {
    int o = blockIdx.x;
    int tid = threadIdx.x, lane = tid & 63, g = tid >> 6;
    int c = tid;
    const float* pw = w + ((size_t)o * CC + c) * 9;
#pragma unroll
    for (int tap = 0; tap < 9; ++tap) {
        u64 m = __ballot(pw[tap] > 0.0f);
        if (lane == 0) wp[(size_t)o * WPO + tap * 4 + g] = m;
    }
}

// ---------------------------------------------------------------------------
// K2/K5: XNOR-popcount 3x3 conv, register sliding-window version.
// grid (4 rowtiles, 4 oblocks, 32 n), block 256 (4 waves).
// Each wave: 2 output rows (r = rt*8 + wid*2 .. +1), lane = output channel.
// Weights (36 u64) + 4x3x4 u64 input window in registers; LDS only streams
// one new column (8 x ds_read_b128) per output column.
// MODE 0: accumulate exact int stats of v. MODE 1: double stats of (v + res).
// ---------------------------------------------------------------------------

// one tap-row: 4 words of (window row wr of slot S) ^ (weight row twr, col dc)
#define T4(S, wr, twr, dc, X) \
    X##0 += __popcll(W[S][wr][0] ^ wreg[((twr)*3+(dc))*4+0]); \
    X##1 += __popcll(W[S][wr][1] ^ wreg[((twr)*3+(dc))*4+1]); \
    X##2 += __popcll(W[S][wr][2] ^ wreg[((twr)*3+(dc))*4+2]); \
    X##3 += __popcll(W[S][wr][3] ^ wreg[((twr)*3+(dc))*4+3]);

// all taps of weight-column dc against window slot S, for both output rows
#define SLOTCOL(S, dc) \
    if (upA) { T4(S, 0, 0, dc, a) } \
    T4(S, 1, 1, dc, a) \
    T4(S, 2, 2, dc, a) \
    T4(S, 1, 0, dc, b) \
    T4(S, 2, 1, dc, b) \
    if (dnB) { T4(S, 3, 2, dc, b) }

// load column c of the LDS tile into ring slot S (4 rows x 4 words)
#define LOADSLOT(S, c) { \
    ulonglong2 t0, t1; \
    t0 = *(const ulonglong2*)&lin[lr0+0][c][0]; t1 = *(const ulonglong2*)&lin[lr0+0][c][2]; \
    W[S][0][0]=t0.x; W[S][0][1]=t0.y; W[S][0][2]=t1.x; W[S][0][3]=t1.y; \
    t0 = *(const ulonglong2*)&lin[lr0+1][c][0]; t1 = *(const ulonglong2*)&lin[lr0+1][c][2]; \
    W[S][1][0]=t0.x; W[S][1][1]=t0.y; W[S][1][2]=t1.x; W[S][1][3]=t1.y; \
    t0 = *(const ulonglong2*)&lin[lr0+2][c][0]; t1 = *(const ulonglong2*)&lin[lr0+2][c][2]; \
    W[S][2][0]=t0.x; W[S][2][1]=t0.y; W[S][2][2]=t1.x; W[S][2][3]=t1.y; \
    t0 = *(const ulonglong2*)&lin[lr0+3][c][0]; t1 = *(const ulonglong2*)&lin[lr0+3][c][2]; \
    W[S][3][0]=t0.x; W[S][3][1]=t0.y; W[S][3][2]=t1.x; W[S][3][3]=t1.y; }

#define COLUMN(c, SP, SQ, SN, HASP, HASN) { \
    int a0=0,a1=0,a2=0,a3=0,b0=0,b1=0,b2=0,b3=0; \
    if (HASP) { SLOTCOL(SP, 0) } \
    SLOTCOL(SQ, 1) \
    if (HASN) { SLOTCOL(SN, 2) } \
    const int nc = (HASP) + 1 + (HASN); \
    int dotA = 256*nrA*nc - 2*(a0+a1+a2+a3); \
    int dotB = 256*nrB*nc - 2*(b0+b1+b2+b3); \
    vrowA[(size_t)(c)*CC] = (short)dotA; \
    vrowB[(size_t)(c)*CC] = (short)dotB; \
    if (MODE == 0) { \
        ts += (double)(dotA + dotB); \
        tq += (double)(dotA*dotA) + (double)(dotB*dotB); \
    } else { \
        float u = (float)dotA + resA[c]; \
        float v = (float)dotB + resB[c]; \
        ts += (double)u + (double)v; \
        tq += (double)u*(double)u + (double)v*(double)v; } }

template<int MODE>
__global__ __launch_bounds__(256, 2) void binconv(
    const u64* __restrict__ xp, const u64* __restrict__ wp,
    short* __restrict__ vout, const float* __restrict__ xres,
    int* __restrict__ s_i, u64* __restrict__ s_q,
    double* __restrict__ s2s, double* __restrict__ s2q)
{
    __shared__ u64 lin[10][28][4];            // rows r0-1 .. r0+8
    __shared__ double reds[4][64];
    __shared__ double redq[4][64];

    int tid = threadIdx.x, lane = tid & 63, wid = tid >> 6;
    int rt = blockIdx.x, ob = blockIdx.y, n = blockIdx.z;
    int r0 = rt * 8;
    int o = ob * 64 + lane;

    // stage input rows r0-1 .. r0+8 into LDS (16B chunks, coalesced)
    for (int idx = tid; idx < 10 * 56; idx += 256) {
        int row = idx / 56, off = idx % 56;   // off in 16B units
        int gr = r0 - 1 + row;
        if (gr >= 0 && gr < HH) {
            ulonglong2 t = *(const ulonglong2*)(xp + ((size_t)n * PP + gr * WW) * 4 + off * 2);
            *(ulonglong2*)((u64*)&lin[row][0][0] + off * 2) = t;
        }
    }
    __syncthreads();

    int r = r0 + wid * 2;                     // first output row of this wave
    bool act = (r < HH);                      // tail rowtile: waves 2,3 idle
    double ts = 0.0, tq = 0.0;

    if (act) {
        // weights -> registers (36 u64)
        u64 wreg[36];
        {
            const ulonglong2* wv = (const ulonglong2*)(wp + (size_t)o * WPO);
#pragma unroll
            for (int k = 0; k < 18; ++k) { ulonglong2 t = wv[k]; wreg[2*k] = t.x; wreg[2*k+1] = t.y; }
        }

        const int lr0 = wid * 2;              // lin row of global row r-1
        const bool upA = (r > 0);             // row A has dr=-1
        const bool dnB = (r + 1 < HH - 1);    // row B has dr=+1
        const int nrA = 2 + (upA ? 1 : 0);
        const int nrB = 2 + (dnB ? 1 : 0);

        const float* resA = (MODE == 1) ? (xres + ((size_t)n * CC + o) * PP + r * WW) : nullptr;
        const float* resB = (MODE == 1) ? (resA + WW) : nullptr;
        short* vrowA = vout + ((size_t)n * PP + (size_t)r * WW) * CC + o;
        short* vrowB = vrowA + (size_t)WW * CC;

        u64 W[3][4][4];                       // ring: slot = col % 3

        LOADSLOT(0, 0)
        LOADSLOT(1, 1)
        COLUMN(0, 0, 0, 1, 0, 1)              // c=0: no prev col
        LOADSLOT(2, 2)
#pragma unroll 1
        for (int m = 0; m < 8; ++m) {
            int c = 3 * m;
            COLUMN(c + 1, 0, 1, 2, 1, 1)
            LOADSLOT(0, c + 3)
            COLUMN(c + 2, 1, 2, 0, 1, 1)
            LOADSLOT(1, c + 4)
            COLUMN(c + 3, 2, 0, 1, 1, 1)
            LOADSLOT(2, c + 5)
        }
        // slots now hold cols 24(s0), 25(s1), 26(s2)
        COLUMN(25, 0, 1, 2, 1, 1)
        LOADSLOT(0, 27)
        COLUMN(26, 1, 2, 0, 1, 1)
        COLUMN(27, 2, 0, 0, 1, 0)             // c=27: no next col
    }

    reds[wid][lane] = ts; redq[wid][lane] = tq;
    __syncthreads();
    if (wid == 0) {
        double S = reds[0][lane] + reds[1][lane] + reds[2][lane] + reds[3][lane];
        double Q = redq[0][lane] + redq[1][lane] + redq[2][lane] + redq[3][lane];
        if (MODE == 0) {
            atomicAdd(&s_i[o], (int)S);
            atomicAdd(&s_q[o], (u64)Q);
        } else {
            atomicAdd(&s2s[o], S);
            atomicAdd(&s2q[o], Q);
        }
    }
}

// ---------------------------------------------------------------------------
// K3: BN affine params.  sign(bn(v)) == (A*v + B > 0)
// ---------------------------------------------------------------------------
__global__ __launch_bounds__(256) void bnprep1(const int* __restrict__ s_i, const u64* __restrict__ s_q,
                                               const float* __restrict__ gamma, const float* __restrict__ beta,
                                               float* __restrict__ A, float* __restrict__ B) {
    int c = threadIdx.x;
    double mean = (double)s_i[c] * (1.0 / NHW);
    double msq  = (double)s_q[c] * (1.0 / NHW);
    double var  = msq - mean * mean;
    double istd = 1.0 / sqrt(var + 1e-5);
    double a = (double)gamma[c] * istd;
    A[c] = (float)a;
    B[c] = (float)((double)beta[c] - mean * a);
}

__global__ __launch_bounds__(256) void bnprep2(const double* __restrict__ ss, const double* __restrict__ sq,
                                               const float* __restrict__ gamma, const float* __restrict__ beta,
                                               float* __restrict__ SC, float* __restrict__ BI) {
    int c = threadIdx.x;
    double mean = ss[c] * (1.0 / NHW);
    double msq  = sq[c] * (1.0 / NHW);
    double var  = msq - mean * mean;
    double istd = 1.0 / sqrt(var + 1e-5);
    double a = (double)gamma[c] * istd;
    SC[c] = (float)a;
    BI[c] = (float)((double)beta[c] - mean * a);
}

// ---------------------------------------------------------------------------
// K4: sign(BN1(v1)) -> bit-pack for conv2. grid (49, 32), block 256.
// ---------------------------------------------------------------------------
__global__ __launch_bounds__(256) void repack(const short* __restrict__ v1,
                                              const float* __restrict__ A, const float* __restrict__ B,
                                              u64* __restrict__ xp2) {
    int pt = blockIdx.x, n = blockIdx.y;
    int tid = threadIdx.x, lane = tid & 63, g = tid >> 6;
    int c = g * 64 + lane;
    float a = A[c], b = B[c];
#pragma unroll
    for (int i = 0; i < 16; ++i) {
        int p = pt * 16 + i;
        int v = v1[((size_t)n * PP + p) * CC + c];
        u64 m = __ballot(fmaf(a, (float)v, b) > 0.0f);
        if (lane == 0) xp2[((size_t)n * PP + p) * 4 + g] = m;
    }
}

// ---------------------------------------------------------------------------
// K7: out = clip(SC*(v2 + x) + BI, -1, 1), NHWC int16 -> NCHW f32 via LDS transpose
// ---------------------------------------------------------------------------
__global__ __launch_bounds__(256) void finalize(const short* __restrict__ v2, const float* __restrict__ x,
                                                const float* __restrict__ SC, const float* __restrict__ BI,
                                                float* __restrict__ out) {
    __shared__ short t[64 * 66];
    int ct = blockIdx.x, pt = blockIdx.y, n = blockIdx.z;
    int p0 = pt * 64, c0 = ct * 64;
    int tid = threadIdx.x;
    for (int idx = tid; idx < 64 * 64; idx += 256) {
        int i = idx >> 6, j = idx & 63;
        int p = p0 + i;
        if (p < PP) t[i * 66 + j] = v2[((size_t)n * PP + p) * CC + c0 + j];
    }
    __syncthreads();
    int pl = tid & 63;
    int p = p0 + pl;
    if (p < PP) {
        for (int cl = tid >> 6; cl < 64; cl += 4) {
            int c = c0 + cl;
            float val = (float)t[pl * 66 + cl] + x[((size_t)n * CC + c) * PP + p];
            float r = fmaf(SC[c], val, BI[c]);
            r = fminf(fmaxf(r, -1.0f), 1.0f);
            out[((size_t)n * CC + c) * PP + p] = r;
        }
    }
}

// ---------------------------------------------------------------------------
extern "C" void kernel_launch(void* const* d_in, const int* in_sizes, int n_in,
                              void* d_out, int out_size, void* d_ws, size_t ws_size,
                              hipStream_t stream) {
    (void)in_sizes; (void)n_in; (void)out_size; (void)ws_size;
    const float* x   = (const float*)d_in[0];
    const float* w1  = (const float*)d_in[1];
    const float* g1  = (const float*)d_in[2];
    const float* b1  = (const float*)d_in[3];
    const float* w2  = (const float*)d_in[4];
    const float* g2  = (const float*)d_in[5];
    const float* b2  = (const float*)d_in[6];
    float* out = (float*)d_out;

    char* ws = (char*)d_ws;
    u64*    xp1 = (u64*)(ws + 0);            //   802816 B
    u64*    xp2 = (u64*)(ws + 802816);       //   802816 B
    u64*    wp1 = (u64*)(ws + 1605632);      //    73728 B
    u64*    wp2 = (u64*)(ws + 1679360);      //    73728 B
    int*    s1i = (int*)(ws + 1753088);      //     1024 B
    u64*    s1q = (u64*)(ws + 1754112);      //     2048 B
    double* s2s = (double*)(ws + 1756160);   //     2048 B
    double* s2q = (double*)(ws + 1758208);   //     2048 B
    float*  bnA = (float*)(ws + 1760256);    //     1024 B
    float*  bnB = (float*)(ws + 1761280);    //     1024 B
    float*  sc2 = (float*)(ws + 1762304);    //     1024 B
    float*  bi2 = (float*)(ws + 1763328);    //     1024 B
    short*  v12 = (short*)(ws + 1764352);    // 12845056 B (v1, then reused as v2)

    zero_stats<<<1, 256, 0, stream>>>(s1i, s1q, s2s, s2q);
    pack_x<<<dim3(28, 32), 256, 0, stream>>>(x, xp1);
    pack_w<<<256, 256, 0, stream>>>(w1, wp1);
    pack_w<<<256, 256, 0, stream>>>(w2, wp2);
    binconv<0><<<dim3(4, 4, 32), 256, 0, stream>>>(xp1, wp1, v12, nullptr, s1i, s1q, nullptr, nullptr);
    bnprep1<<<1, 256, 0, stream>>>(s1i, s1q, g1, b1, bnA, bnB);
    repack<<<dim3(49, 32), 256, 0, stream>>>(v12, bnA, bnB, xp2);
    binconv<1><<<dim3(4, 4, 32), 256, 0, stream>>>(xp2, wp2, v12, x, nullptr, nullptr, s2s, s2q);
    bnprep2<<<1, 256, 0, stream>>>(s2s, s2q, g2, b2, sc2, bi2);
    finalize<<<dim3(4, 13, 32), 256, 0, stream>>>(v12, x, sc2, bi2, out);
}

// Round 3
// 123.929 us; speedup vs baseline: 1.4820x; 1.4820x over previous
//
#include <hip/hip_runtime.h>
#include <stdint.h>

typedef unsigned long long u64;

// Problem constants
#define NN 32
#define CC 256
#define HH 28
#define WW 28
#define PP 784          // H*W
#define NHW 25088       // N*H*W  (per-channel BN count)
#define WPO 36          // packed words per output channel: 9 taps * 4 words

// ---------------------------------------------------------------------------
// K1: binarize + bit-pack x (NCHW f32) -> xp [N][P][4] u64 (bit c%64 of word c/64)
// ---------------------------------------------------------------------------
__global__ __launch_bounds__(256) void pack_x(const float* __restrict__ x, u64* __restrict__ xp) {
    int h = blockIdx.x, n = blockIdx.y;
    int tid = threadIdx.x, lane = tid & 63, g = tid >> 6;
    int c = tid;
    const float* px = x + (((size_t)n * CC + c) * PP) + h * WW;
    float vals[28];
#pragma unroll
    for (int k = 0; k < 7; ++k) ((float4*)vals)[k] = ((const float4*)px)[k];
    u64* dst = xp + ((size_t)n * PP + h * WW) * 4 + g;
#pragma unroll
    for (int i = 0; i < 28; ++i) {
        u64 m = __ballot(vals[i] > 0.0f);
        if (lane == 0) dst[(size_t)i * 4] = m;
    }
}

// ---------------------------------------------------------------------------
// K1b: pack BOTH weight tensors + zero the stats accumulators.
// grid (256 o, 2 which), block 256.
// ---------------------------------------------------------------------------
__global__ __launch_bounds__(256) void pack_wz(const float* __restrict__ w1, const float* __restrict__ w2,
                                               u64* __restrict__ wp1, u64* __restrict__ wp2,
                                               int* s1i, u64* s1q, double* s2s, double* s2q) {
    int o = blockIdx.x, which = blockIdx.y;
    int tid = threadIdx.x, lane = tid & 63, g = tid >> 6;
    if (o == 0 && which == 0) {   // fold in stats zeroing (stream-ordered before binconv)
        s1i[tid] = 0; s1q[tid] = 0ull; s2s[tid] = 0.0; s2q[tid] = 0.0;
    }
    const float* w = which ? w2 : w1;
    u64* wp = which ? wp2 : wp1;
    const float* pw = w + ((size_t)o * CC + tid) * 9;
#pragma unroll
    for (int tap = 0; tap < 9; ++tap) {
        u64 m = __ballot(pw[tap] > 0.0f);
        if (lane == 0) wp[(size_t)o * WPO + tap * 4 + g] = m;
    }
}

// ---------------------------------------------------------------------------
// K2/K5: XNOR-popcount 3x3 conv — transposed-FIR accumulator rotation.
// grid (7 rowtiles, 4 oblocks, 32 n), block 256 (4 waves).
// Each wave: ONE output row (r = rt*4 + wid), lane = output channel (ob*64+lane).
// Weights: 36 u64 in registers. Input: stream one column (3 rows x 4 u64,
// broadcast ds_read_b128) per iteration; rotate 3 int accumulators
// (outputs c-1, c, c+1). Live VGPR ~110 -> no spill, no ring buffer.
// MODE 0: exact int stats of v. MODE 1: float stats of (v + residual).
// ---------------------------------------------------------------------------

#define POP4(acc, T, WB) \
    acc += __popcll(T[0] ^ wreg[(WB)+0]) + __popcll(T[1] ^ wreg[(WB)+1]) \
         + __popcll(T[2] ^ wreg[(WB)+2]) + __popcll(T[3] ^ wreg[(WB)+3]);

#define LOADROW(T, lrow, ccc) { \
    ulonglong2 u0 = *(const ulonglong2*)&lin[lrow][ccc][0]; \
    ulonglong2 u1 = *(const ulonglong2*)&lin[lrow][ccc][2]; \
    T[0] = u0.x; T[1] = u0.y; T[2] = u1.x; T[3] = u1.y; }

// full column: accumulate into P (out cc-1, wcol2), C (out cc, wcol1), N (out cc+1, wcol0)
#define COLBODY(ccc, AP, AC, AN) { \
    u64 t0[4], t1[4], t2[4]; \
    LOADROW(t1, wid + 1, ccc) \
    if (rtop) { LOADROW(t0, wid, ccc) } \
    if (rbot) { LOADROW(t2, wid + 2, ccc) } \
    if (rtop) { POP4(AN, t0, 0)  POP4(AC, t0, 4)  POP4(AP, t0, 8)  } \
    POP4(AN, t1, 12) POP4(AC, t1, 16) POP4(AP, t1, 20) \
    if (rbot) { POP4(AN, t2, 24) POP4(AC, t2, 28) POP4(AP, t2, 32) } }

#define EMIT(emc, A) { \
    int K = ((emc) == 0 || (emc) == 27) ? bb2 : bb3; \
    int dot = K - 2 * (A); \
    *vptr = (short)dot; vptr += CC; \
    if (MODE == 0) { tsi += dot; tqi += dot * dot; } \
    else { float u = (float)dot + resrow[emc]; tsf += u; tqf = fmaf(u, u, tqf); } }

template<int MODE>
__global__ __launch_bounds__(256, 3) void binconv(
    const u64* __restrict__ xp, const u64* __restrict__ wp,
    short* __restrict__ vout, const float* __restrict__ xres,
    int* __restrict__ s_i, u64* __restrict__ s_q,
    double* __restrict__ s2s, double* __restrict__ s2q)
{
    __shared__ u64 lin[6][28][4];             // global rows r0-1 .. r0+4
    __shared__ double reds[4][64];
    __shared__ double redq[4][64];

    int tid = threadIdx.x, lane = tid & 63, wid = tid >> 6;
    int rt = blockIdx.x, ob = blockIdx.y, n = blockIdx.z;
    int r0 = rt * 4;
    int o = ob * 64 + lane;

    // stage 6 input rows (contiguous 5376B region of xp, coalesced 16B chunks)
    for (int idx = tid; idx < 6 * 56; idx += 256) {
        int row = idx / 56, off = idx % 56;   // off in 16B units
        int gr = r0 - 1 + row;
        if (gr >= 0 && gr < HH) {
            ulonglong2 t = *(const ulonglong2*)(xp + ((size_t)n * PP + gr * WW) * 4 + off * 2);
            *(ulonglong2*)((u64*)lin + row * 112 + off * 2) = t;
        }
    }

    // weights -> registers (36 u64 = 72 VGPR)
    u64 wreg[36];
    {
        const ulonglong2* wv = (const ulonglong2*)(wp + (size_t)o * WPO);
#pragma unroll
        for (int k = 0; k < 18; ++k) { ulonglong2 t = wv[k]; wreg[2*k] = t.x; wreg[2*k+1] = t.y; }
    }
    __syncthreads();

    int r = r0 + wid;                         // this wave's output row (always < 28)
    const bool rtop = (r > 0), rbot = (r < HH - 1);
    const int nr = 1 + (int)rtop + (int)rbot;
    const int bb3 = 256 * nr * 3, bb2 = 256 * nr * 2;

    short* vptr = vout + ((size_t)n * PP + (size_t)r * WW) * CC + o;
    const float* resrow = (MODE == 1) ? (xres + ((size_t)n * CC + o) * PP + r * WW) : nullptr;

    int tsi = 0, tqi = 0; float tsf = 0.0f, tqf = 0.0f;
    int a = 0, b = 0, c = 0;

    // peel input col 0: contributes to out0 (wcol1 -> b) and out1 (wcol0 -> c)
    {
        u64 t0[4], t1[4], t2[4];
        LOADROW(t1, wid + 1, 0)
        if (rtop) { LOADROW(t0, wid, 0) }
        if (rbot) { LOADROW(t2, wid + 2, 0) }
        if (rtop) { POP4(c, t0, 0)  POP4(b, t0, 4)  }
        POP4(c, t1, 12) POP4(b, t1, 16)
        if (rbot) { POP4(c, t2, 24) POP4(b, t2, 28) }
    }

#pragma unroll 1
    for (int m = 0; m < 9; ++m) {
        int cc = 3 * m + 1;
        COLBODY(cc,     b, c, a)  EMIT(cc - 1, b)  b = 0;
        COLBODY(cc + 1, c, a, b)  EMIT(cc,     c)  c = 0;
        COLBODY(cc + 2, a, b, c)  EMIT(cc + 1, a)  a = 0;
    }
    EMIT(27, b)                                // out 27 completed by input col 27

    reds[wid][lane] = (MODE == 0) ? (double)tsi : (double)tsf;
    redq[wid][lane] = (MODE == 0) ? (double)tqi : (double)tqf;
    __syncthreads();
    if (wid == 0) {
        double S = reds[0][lane] + reds[1][lane] + reds[2][lane] + reds[3][lane];
        double Q = redq[0][lane] + redq[1][lane] + redq[2][lane] + redq[3][lane];
        if (MODE == 0) {
            atomicAdd(&s_i[o], (int)S);
            atomicAdd(&s_q[o], (u64)Q);
        } else {
            atomicAdd(&s2s[o], S);
            atomicAdd(&s2q[o], Q);
        }
    }
}

// ---------------------------------------------------------------------------
// K4: sign(BN1(v1)) -> bit-pack for conv2, BN1 params computed inline from
// exact int stats. grid (49, 32), block 256.
// ---------------------------------------------------------------------------
__global__ __launch_bounds__(256) void repack(const short* __restrict__ v1,
                                              const int* __restrict__ s_i, const u64* __restrict__ s_q,
                                              const float* __restrict__ gamma, const float* __restrict__ beta,
                                              u64* __restrict__ xp2) {
    int pt = blockIdx.x, n = blockIdx.y;
    int tid = threadIdx.x, lane = tid & 63, g = tid >> 6;
    int c = tid;
    double mean = (double)s_i[c] * (1.0 / NHW);
    double msq  = (double)s_q[c] * (1.0 / NHW);
    double var  = msq - mean * mean;
    double istd = 1.0 / sqrt(var + 1e-5);
    double ad   = (double)gamma[c] * istd;
    float a = (float)ad;
    float b = (float)((double)beta[c] - mean * ad);
#pragma unroll
    for (int i = 0; i < 16; ++i) {
        int p = pt * 16 + i;
        int v = v1[((size_t)n * PP + p) * CC + c];
        u64 m = __ballot(fmaf(a, (float)v, b) > 0.0f);
        if (lane == 0) xp2[((size_t)n * PP + p) * 4 + g] = m;
    }
}

// ---------------------------------------------------------------------------
// K7: out = clip(SC*(v2 + x) + BI, -1, 1); BN2 params inline from double stats.
// NHWC int16 -> NCHW f32 via LDS transpose. grid (4, 13, 32), block 256.
// ---------------------------------------------------------------------------
__global__ __launch_bounds__(256) void finalize(const short* __restrict__ v2, const float* __restrict__ x,
                                                const double* __restrict__ s2s, const double* __restrict__ s2q,
                                                const float* __restrict__ gamma, const float* __restrict__ beta,
                                                float* __restrict__ out) {
    __shared__ short t[64 * 66];
    __shared__ float scs[64], bis[64];
    int ct = blockIdx.x, pt = blockIdx.y, n = blockIdx.z;
    int p0 = pt * 64, c0 = ct * 64;
    int tid = threadIdx.x;
    if (tid < 64) {
        int c = c0 + tid;
        double mean = s2s[c] * (1.0 / NHW);
        double msq  = s2q[c] * (1.0 / NHW);
        double var  = msq - mean * mean;
        double istd = 1.0 / sqrt(var + 1e-5);
        double ad   = (double)gamma[c] * istd;
        scs[tid] = (float)ad;
        bis[tid] = (float)((double)beta[c] - mean * ad);
    }
    for (int idx = tid; idx < 64 * 64; idx += 256) {
        int i = idx >> 6, j = idx & 63;
        int p = p0 + i;
        if (p < PP) t[i * 66 + j] = v2[((size_t)n * PP + p) * CC + c0 + j];
    }
    __syncthreads();
    int pl = tid & 63;
    int p = p0 + pl;
    if (p < PP) {
        for (int cl = tid >> 6; cl < 64; cl += 4) {
            int c = c0 + cl;
            float val = (float)t[pl * 66 + cl] + x[((size_t)n * CC + c) * PP + p];
            float r = fmaf(scs[cl], val, bis[cl]);
            r = fminf(fmaxf(r, -1.0f), 1.0f);
            out[((size_t)n * CC + c) * PP + p] = r;
        }
    }
}

// ---------------------------------------------------------------------------
extern "C" void kernel_launch(void* const* d_in, const int* in_sizes, int n_in,
                              void* d_out, int out_size, void* d_ws, size_t ws_size,
                              hipStream_t stream) {
    (void)in_sizes; (void)n_in; (void)out_size; (void)ws_size;
    const float* x   = (const float*)d_in[0];
    const float* w1  = (const float*)d_in[1];
    const float* g1  = (const float*)d_in[2];
    const float* b1  = (const float*)d_in[3];
    const float* w2  = (const float*)d_in[4];
    const float* g2  = (const float*)d_in[5];
    const float* b2  = (const float*)d_in[6];
    float* out = (float*)d_out;

    char* ws = (char*)d_ws;
    u64*    xp1 = (u64*)(ws + 0);            //   802816 B
    u64*    xp2 = (u64*)(ws + 802816);       //   802816 B
    u64*    wp1 = (u64*)(ws + 1605632);      //    73728 B
    u64*    wp2 = (u64*)(ws + 1679360);      //    73728 B
    int*    s1i = (int*)(ws + 1753088);      //     1024 B
    u64*    s1q = (u64*)(ws + 1754112);      //     2048 B
    double* s2s = (double*)(ws + 1756160);   //     2048 B
    double* s2q = (double*)(ws + 1758208);   //     2048 B
    short*  v12 = (short*)(ws + 1764352);    // 12845056 B (v1, then reused as v2)

    pack_wz<<<dim3(256, 2), 256, 0, stream>>>(w1, w2, wp1, wp2, s1i, s1q, s2s, s2q);
    pack_x<<<dim3(28, 32), 256, 0, stream>>>(x, xp1);
    binconv<0><<<dim3(7, 4, 32), 256, 0, stream>>>(xp1, wp1, v12, nullptr, s1i, s1q, nullptr, nullptr);
    repack<<<dim3(49, 32), 256, 0, stream>>>(v12, s1i, s1q, g1, b1, xp2);
    binconv<1><<<dim3(7, 4, 32), 256, 0, stream>>>(xp2, wp2, v12, x, nullptr, nullptr, s2s, s2q);
    finalize<<<dim3(4, 13, 32), 256, 0, stream>>>(v12, x, s2s, s2q, g2, b2, out);
}